// Round 1
// baseline (474.079 us; speedup 1.0000x reference)
//
#include <hip/hip_runtime.h>
#include <hip/hip_bf16.h>
#include <math.h>

// Problem dims (fixed): T=512, B=256, I=128, H=256
#define TT 512
#define BB 256
#define II 128
#define HH 256

// ---------------------------------------------------------------------------
// Kernel 1: input projection  xi[m][n] = sum_k x[m][k]*Wi[n][k] + bh[n]
//   M = T*B = 131072, K = 128, N = 256.  Written into d_out (later overwritten
//   in-place by the recurrence with h_t).
//   Block tile: 64 M x 64 N, 256 threads, 4x4 register blocking.
// ---------------------------------------------------------------------------
__global__ __launch_bounds__(256) void proj_kernel(
    const float* __restrict__ x, const float* __restrict__ Wi,
    const float* __restrict__ bh, float* __restrict__ out)
{
    // xt[k][r]: transposed x tile, stride 68 floats (272B: 16B-aligned rows,
    // conflict-free 4x-broadcast b128 reads). wt[k][j]: Wi tile, stride 64.
    __shared__ float xt[128][68];
    __shared__ float wt[128][64];

    const int tid = threadIdx.x;
    const int m0 = blockIdx.x * 64;   // 0..2047 -> rows
    const int j0 = blockIdx.y * 64;   // 0..3    -> cols

    // ---- stage tiles ----
    {
        const int r  = tid & 63;       // row within tile (also Wi row j0+r)
        const int kc = tid >> 6;       // 0..3, each covers 32 k
        const float* xsrc = x  + (size_t)(m0 + r) * II + kc * 32;
        const float* wsrc = Wi + (size_t)(j0 + r) * II + kc * 32;
#pragma unroll
        for (int u = 0; u < 8; ++u) {
            float4 v = *(const float4*)(xsrc + u * 4);
            int k = kc * 32 + u * 4;
            xt[k + 0][r] = v.x; xt[k + 1][r] = v.y;
            xt[k + 2][r] = v.z; xt[k + 3][r] = v.w;
        }
#pragma unroll
        for (int u = 0; u < 8; ++u) {
            float4 v = *(const float4*)(wsrc + u * 4);
            int k = kc * 32 + u * 4;
            wt[k + 0][r] = v.x; wt[k + 1][r] = v.y;
            wt[k + 2][r] = v.z; wt[k + 3][r] = v.w;
        }
    }
    __syncthreads();

    // ---- compute 4x4 per thread ----
    const int ty = tid >> 4, tx = tid & 15;
    const int r0 = ty * 4, c0 = tx * 4;
    float acc[4][4] = {};
#pragma unroll 4
    for (int k = 0; k < 128; ++k) {
        float4 a = *(const float4*)&xt[k][r0];
        float4 b = *(const float4*)&wt[k][c0];
        float av[4] = {a.x, a.y, a.z, a.w};
        float bv[4] = {b.x, b.y, b.z, b.w};
#pragma unroll
        for (int i = 0; i < 4; ++i)
#pragma unroll
            for (int j = 0; j < 4; ++j)
                acc[i][j] += av[i] * bv[j];
    }

    // ---- epilogue: bias + store ----
    float4 bias = *(const float4*)(bh + j0 + c0);
    float bvv[4] = {bias.x, bias.y, bias.z, bias.w};
#pragma unroll
    for (int i = 0; i < 4; ++i) {
        float4 o;
        o.x = acc[i][0] + bvv[0];
        o.y = acc[i][1] + bvv[1];
        o.z = acc[i][2] + bvv[2];
        o.w = acc[i][3] + bvv[3];
        *(float4*)(out + (size_t)(m0 + r0 + i) * HH + j0 + c0) = o;
    }
}

// ---------------------------------------------------------------------------
// Kernel 2: recurrence. One block per batch row b. 512 threads = 8 waves.
//   Thread (lane j4 = tid&63, wave kq = tid>>6):
//     owns output columns j = j4*4..j4*4+3 and k-slice [kq*32, kq*32+32)
//     holds Wh[j][k-slice] in registers (4 x 8 float4 = 128 VGPRs).
//   Per step: broadcast-read h from LDS, 128 FMAs, write 4 partials,
//   barrier, 8-way reduce + tanh by tid<256, barrier.
//   xi read from io (d_out) and overwritten in place with h_t.
// ---------------------------------------------------------------------------
__global__ __launch_bounds__(512) void rec_kernel(
    const float* __restrict__ Wh, const float* __restrict__ h0,
    float* __restrict__ io)
{
    __shared__ float h[HH];
    __shared__ float part[8][HH];

    const int tid  = threadIdx.x;
    const int b    = blockIdx.x;
    const int lane = tid & 63;
    const int kq   = tid >> 6;     // wave id, 0..7
    const int jb   = lane * 4;     // first of 4 output columns
    const int kb   = kq * 32;      // k-slice base

    // persistent Wh fragment in registers
    float4 w[4][8];
#pragma unroll
    for (int c = 0; c < 4; ++c)
#pragma unroll
        for (int m = 0; m < 8; ++m)
            w[c][m] = *(const float4*)(Wh + (size_t)(jb + c) * HH + kb + m * 4);

    if (tid < HH) h[tid] = h0[(size_t)b * HH + tid];
    __syncthreads();

    size_t ofs = (size_t)b * HH;   // advances by B*H per step
    for (int t = 0; t < TT; ++t) {
        // prefetch xi for this step (consumed in reduce phase)
        float xr = 0.f;
        if (tid < HH) xr = io[ofs + tid];

        // broadcast-read current h slice
        float4 hv[8];
#pragma unroll
        for (int m = 0; m < 8; ++m)
            hv[m] = *(const float4*)&h[kb + m * 4];

        // 4 columns x 32 k FMAs
        float acc[4];
#pragma unroll
        for (int c = 0; c < 4; ++c) {
            float s = 0.f;
#pragma unroll
            for (int m = 0; m < 8; ++m) {
                s += w[c][m].x * hv[m].x;
                s += w[c][m].y * hv[m].y;
                s += w[c][m].z * hv[m].z;
                s += w[c][m].w * hv[m].w;
            }
            acc[c] = s;
        }
        *(float4*)&part[kq][jb] = make_float4(acc[0], acc[1], acc[2], acc[3]);
        __syncthreads();

        if (tid < HH) {
            float s = xr;
#pragma unroll
            for (int q = 0; q < 8; ++q) s += part[q][tid];
            float hn = tanhf(s);
            h[tid] = hn;
            io[ofs + tid] = hn;
        }
        __syncthreads();
        ofs += (size_t)BB * HH;
    }
}

extern "C" void kernel_launch(void* const* d_in, const int* in_sizes, int n_in,
                              void* d_out, int out_size, void* d_ws, size_t ws_size,
                              hipStream_t stream) {
    const float* x  = (const float*)d_in[0];  // [T,B,I]
    const float* h0 = (const float*)d_in[1];  // [B,H]
    const float* Wi = (const float*)d_in[2];  // [H,I]
    const float* Wh = (const float*)d_in[3];  // [H,H]
    const float* bh = (const float*)d_in[4];  // [H]
    float* out = (float*)d_out;               // [T,B,H]

    // Phase 1: xi = x @ Wi^T + bh  -> out
    dim3 pgrid(TT * BB / 64, HH / 64);
    proj_kernel<<<pgrid, 256, 0, stream>>>(x, Wi, bh, out);

    // Phase 2: sequential recurrence, in-place on out
    rec_kernel<<<BB, 512, 0, stream>>>(Wh, h0, out);
}